// Round 1
// baseline (756.746 us; speedup 1.0000x reference)
//
#include <hip/hip_runtime.h>
#include <hip/hip_bf16.h>
#include <stdint.h>

typedef unsigned short ushort_t;
typedef __attribute__((ext_vector_type(8))) short short8;
typedef __attribute__((ext_vector_type(4))) float floatx4;
typedef __attribute__((ext_vector_type(4))) unsigned short ushortx4;

#define N_ROWS 65536
#define N64 4194304LL   // 65536*64

__device__ __forceinline__ ushort_t f2bf(float f) {
    union { float f; unsigned int i; } v; v.f = f;
    unsigned int u = v.i;
    return (ushort_t)((u + 0x7fffu + ((u >> 16) & 1u)) >> 16);
}

__device__ __forceinline__ float fast_tanh(float x) {
    float ax = fabsf(x);
    float t = __expf(-2.f * ax);
    float r = (1.f - t) / (1.f + t);
    return x < 0.f ? -r : r;
}

#define GLD16(gp, lp) __builtin_amdgcn_global_load_lds( \
    (const __attribute__((address_space(1))) unsigned int*)(gp), \
    (__attribute__((address_space(3))) unsigned int*)(lp), 16, 0, 0)

// ---------------- prep: fp32 -> bf16 convert (vectorized) ----------------
__global__ void cvt_bf16_kernel(const float4* __restrict__ src,
                                ushortx4* __restrict__ dst, int n4) {
    int i = blockIdx.x * 256 + threadIdx.x;
    if (i < n4) {
        float4 v = src[i];
        ushortx4 o;
        o.x = f2bf(v.x); o.y = f2bf(v.y); o.z = f2bf(v.z); o.w = f2bf(v.w);
        dst[i] = o;
    }
}

// ---------------- prep: transpose [K,M] fp32 -> [M,K] bf16 ----------------
// grid: (M/64, K/64), block 256
__global__ void transpose_cvt_kernel(const float* __restrict__ src,
                                     ushort_t* __restrict__ dst, int K, int M) {
    __shared__ ushort_t tile[64][65];
    const int m0 = blockIdx.x * 64, k0 = blockIdx.y * 64;
    const int tr = threadIdx.x >> 6, tc = threadIdx.x & 63;
#pragma unroll
    for (int i = 0; i < 16; i++) {
        int kk = i * 4 + tr;
        tile[kk][tc] = f2bf(src[(long)(k0 + kk) * M + m0 + tc]);
    }
    __syncthreads();
#pragma unroll
    for (int i = 0; i < 16; i++) {
        int mm = i * 4 + tr;
        dst[(long)(m0 + mm) * K + k0 + tc] = tile[tc][mm];
    }
}

// ---------------- main bf16 GEMM: C = act(A @ Bt^T + bias) ----------------
// A [N,K] bf16 row-major; Bt [M,K] bf16 row-major; C [N,M] bf16.
// 128x128 tile, BK=32, 4 waves of 4x4 16x16x32 MFMA. grid (N/128, M/128).
__global__ __launch_bounds__(256, 2) void gemm_bt_kernel(
    const ushort_t* __restrict__ A, const ushort_t* __restrict__ Bt,
    const float* __restrict__ bias, ushort_t* __restrict__ C,
    int K, int M, int do_tanh) {
    __shared__ ushort_t As[128 * 32];
    __shared__ ushort_t Bs[128 * 32];
    const int tid = threadIdx.x, wave = tid >> 6, lane = tid & 63;
    const long row0 = (long)blockIdx.x * 128;
    const long col0 = (long)blockIdx.y * 128;
    const int srow = wave * 16 + (lane >> 2);
    const int skoff = (lane & 3) * 8;
    const ushort_t* aG = A + (row0 + srow) * K + skoff;
    const ushort_t* bG = Bt + (col0 + srow) * K + skoff;
    ushort_t* asW = As + wave * 16 * 32;
    ushort_t* bsW = Bs + wave * 16 * 32;
    floatx4 acc[4][4];
#pragma unroll
    for (int i = 0; i < 4; i++)
#pragma unroll
        for (int j = 0; j < 4; j++) acc[i][j] = (floatx4){0.f, 0.f, 0.f, 0.f};
    const int wm = (wave & 1) * 64, wn = (wave >> 1) * 64;
    const int fr = lane & 15, q = lane >> 4, kq = q * 8;
    for (int k0 = 0; k0 < K; k0 += 32) {
        GLD16(aG, asW);
        GLD16(aG + (long)64 * K, asW + 64 * 32);
        GLD16(bG, bsW);
        GLD16(bG + (long)64 * K, bsW + 64 * 32);
        aG += 32; bG += 32;
        __syncthreads();
        short8 af[4], bf[4];
#pragma unroll
        for (int i = 0; i < 4; i++) af[i] = *(const short8*)&As[(wm + i * 16 + fr) * 32 + kq];
#pragma unroll
        for (int j = 0; j < 4; j++) bf[j] = *(const short8*)&Bs[(wn + j * 16 + fr) * 32 + kq];
#pragma unroll
        for (int i = 0; i < 4; i++)
#pragma unroll
            for (int j = 0; j < 4; j++)
                acc[i][j] = __builtin_amdgcn_mfma_f32_16x16x32_bf16(af[i], bf[j], acc[i][j], 0, 0, 0);
        __syncthreads();
    }
#pragma unroll
    for (int j = 0; j < 4; j++) {
        const int c = wn + j * 16 + fr;
        const float b = bias[col0 + c];
#pragma unroll
        for (int i = 0; i < 4; i++) {
            const long rb = row0 + wm + i * 16 + q * 4;
#pragma unroll
            for (int r = 0; r < 4; r++) {
                float v = acc[i][j][r] + b;
                if (do_tanh) v = fast_tanh(v);
                C[(rb + r) * M + col0 + c] = f2bf(v);
            }
        }
    }
}

// ---------------- heads: mean & log_var in one pass, fp32 out ----------------
// A = t2 [N,1024]; Mwt/Lwt [64,1024] bf16. grid (N/128, 1).
__global__ __launch_bounds__(256, 2) void heads_kernel(
    const ushort_t* __restrict__ A, const ushort_t* __restrict__ Mwt,
    const ushort_t* __restrict__ Lwt, const float* __restrict__ mb,
    const float* __restrict__ lb, float* __restrict__ out) {
    const int K = 1024;
    __shared__ ushort_t As[128 * 32];
    __shared__ ushort_t Bs[128 * 32];
    const int tid = threadIdx.x, wave = tid >> 6, lane = tid & 63;
    const long row0 = (long)blockIdx.x * 128;
    const int srow = wave * 16 + (lane >> 2);
    const int skoff = (lane & 3) * 8;
    const ushort_t* aG = A + (row0 + srow) * K + skoff;
    const ushort_t* bG0 = Mwt + (long)srow * K + skoff;   // cols 0..63
    const ushort_t* bG1 = Lwt + (long)srow * K + skoff;   // cols 64..127
    ushort_t* asW = As + wave * 16 * 32;
    ushort_t* bsW = Bs + wave * 16 * 32;
    floatx4 acc[4][4];
#pragma unroll
    for (int i = 0; i < 4; i++)
#pragma unroll
        for (int j = 0; j < 4; j++) acc[i][j] = (floatx4){0.f, 0.f, 0.f, 0.f};
    const int wm = (wave & 1) * 64, wn = (wave >> 1) * 64;
    const int fr = lane & 15, q = lane >> 4, kq = q * 8;
    for (int k0 = 0; k0 < K; k0 += 32) {
        GLD16(aG, asW);
        GLD16(aG + (long)64 * K, asW + 64 * 32);
        GLD16(bG0, bsW);
        GLD16(bG1, bsW + 64 * 32);
        aG += 32; bG0 += 32; bG1 += 32;
        __syncthreads();
        short8 af[4], bf[4];
#pragma unroll
        for (int i = 0; i < 4; i++) af[i] = *(const short8*)&As[(wm + i * 16 + fr) * 32 + kq];
#pragma unroll
        for (int j = 0; j < 4; j++) bf[j] = *(const short8*)&Bs[(wn + j * 16 + fr) * 32 + kq];
#pragma unroll
        for (int i = 0; i < 4; i++)
#pragma unroll
            for (int j = 0; j < 4; j++)
                acc[i][j] = __builtin_amdgcn_mfma_f32_16x16x32_bf16(af[i], bf[j], acc[i][j], 0, 0, 0);
        __syncthreads();
    }
#pragma unroll
    for (int j = 0; j < 4; j++) {
        const int c = wn + j * 16 + fr;   // 0..127
        const float b = (c < 64) ? mb[c] : lb[c - 64];
        float* obase = (c < 64) ? (out + c) : (out + N64 + (c - 64));
#pragma unroll
        for (int i = 0; i < 4; i++) {
            const long rb = row0 + wm + i * 16 + q * 4;
#pragma unroll
            for (int r = 0; r < 4; r++) obase[(rb + r) * 64] = acc[i][j][r] + b;
        }
    }
}

// ---------------- fused VQ: z-GEMM + argmin + z_q gather + loss ----------------
// grid N/128 blocks. H [N,1024] bf16, W2t [64,1024] bf16, emb [512,64] fp32.
__global__ __launch_bounds__(256, 1) void vq_kernel(
    const ushort_t* __restrict__ H, const ushort_t* __restrict__ W2t,
    const float* __restrict__ b2, const float* __restrict__ emb,
    ushort_t* __restrict__ Zq, float* __restrict__ lossAcc) {
    const int K = 1024;
    __shared__ ushort_t As[128 * 32];   // 8KB
    __shared__ ushort_t Bs[64 * 32];    // 4KB
    __shared__ ushort_t zb[128 * 64];   // 16KB  z in bf16, A-operand staging
    __shared__ ushort_t ebc[128 * 64];  // 16KB  codebook chunk bf16
    __shared__ float enorm[512];
    __shared__ int ridx[128];
    __shared__ float lred[4];
    const int tid = threadIdx.x, wave = tid >> 6, lane = tid & 63;
    const long row0 = (long)blockIdx.x * 128;
    const int srow = wave * 16 + (lane >> 2), skoff = (lane & 3) * 8;
    const ushort_t* aG = H + (row0 + srow) * K + skoff;
    const ushort_t* bG = W2t + (long)srow * K + skoff;
    ushort_t* asW = As + wave * 16 * 32;
    ushort_t* bsW = Bs + wave * 16 * 32;
    floatx4 acc[2][4];
#pragma unroll
    for (int i = 0; i < 2; i++)
#pragma unroll
        for (int j = 0; j < 4; j++) acc[i][j] = (floatx4){0.f, 0.f, 0.f, 0.f};
    const int fr = lane & 15, q = lane >> 4, kq = q * 8;
    const int wr = wave * 32;
    // ---- z = H @ W2t^T + b2 ----
    for (int k0 = 0; k0 < K; k0 += 32) {
        GLD16(aG, asW);
        GLD16(aG + (long)64 * K, asW + 64 * 32);
        GLD16(bG, bsW);
        aG += 32; bG += 32;
        __syncthreads();
        short8 af[2], bf[4];
#pragma unroll
        for (int i = 0; i < 2; i++) af[i] = *(const short8*)&As[(wr + i * 16 + fr) * 32 + kq];
#pragma unroll
        for (int j = 0; j < 4; j++) bf[j] = *(const short8*)&Bs[(j * 16 + fr) * 32 + kq];
#pragma unroll
        for (int i = 0; i < 2; i++)
#pragma unroll
            for (int j = 0; j < 4; j++)
                acc[i][j] = __builtin_amdgcn_mfma_f32_16x16x32_bf16(af[i], bf[j], acc[i][j], 0, 0, 0);
        __syncthreads();
    }
    // add bias, stage z (bf16) for the distance MFMA
#pragma unroll
    for (int j = 0; j < 4; j++) {
        float bb = b2[j * 16 + fr];
#pragma unroll
        for (int i = 0; i < 2; i++)
#pragma unroll
            for (int r = 0; r < 4; r++) {
                acc[i][j][r] += bb;
                zb[(wr + i * 16 + q * 4 + r) * 64 + j * 16 + fr] = f2bf(acc[i][j][r]);
            }
    }
    // codebook squared norms (fp32, from global)
    for (int c = tid; c < 512; c += 256) {
        const float4* e = (const float4*)(emb + c * 64);
        float s = 0.f;
#pragma unroll
        for (int k = 0; k < 16; k++) { float4 v = e[k]; s += v.x * v.x + v.y * v.y + v.z * v.z + v.w * v.w; }
        enorm[c] = s;
    }
    __syncthreads();
    // z fragments (A-operand layout) — rows of this wave
    short8 za[2][2];
#pragma unroll
    for (int i = 0; i < 2; i++)
#pragma unroll
        for (int h = 0; h < 2; h++)
            za[i][h] = *(const short8*)&zb[(wr + i * 16 + fr) * 64 + h * 32 + kq];
    float minv[8]; int mini[8];
#pragma unroll
    for (int t = 0; t < 8; t++) { minv[t] = 3.0e38f; mini[t] = 0; }
    // ---- dist = ||e||^2 - 2 z.e, chunked 128 codes ----
    for (int ch = 0; ch < 4; ch++) {
        __syncthreads();   // previous chunk's MFMAs done before restage
        const float4* esrc = (const float4*)(emb + ch * 128 * 64);
        for (int g = tid; g < 2048; g += 256) {
            float4 v = esrc[g];
            ushortx4 o;
            o.x = f2bf(v.x); o.y = f2bf(v.y); o.z = f2bf(v.z); o.w = f2bf(v.w);
            *(ushortx4*)&ebc[g * 4] = o;
        }
        __syncthreads();
#pragma unroll
        for (int jt = 0; jt < 8; jt++) {
            const int code = ch * 128 + jt * 16 + fr;
            short8 e0 = *(const short8*)&ebc[(jt * 16 + fr) * 64 + kq];
            short8 e1 = *(const short8*)&ebc[(jt * 16 + fr) * 64 + 32 + kq];
            float en = enorm[code];
#pragma unroll
            for (int i = 0; i < 2; i++) {
                floatx4 s = (floatx4){0.f, 0.f, 0.f, 0.f};
                s = __builtin_amdgcn_mfma_f32_16x16x32_bf16(za[i][0], e0, s, 0, 0, 0);
                s = __builtin_amdgcn_mfma_f32_16x16x32_bf16(za[i][1], e1, s, 0, 0, 0);
#pragma unroll
                for (int r = 0; r < 4; r++) {
                    float d = en - 2.f * s[r];
                    int t = i * 4 + r;
                    if (d < minv[t]) { minv[t] = d; mini[t] = code; }
                }
            }
        }
    }
    // reduce argmin across the 16 lanes that share each output row
#pragma unroll
    for (int m = 1; m < 16; m <<= 1) {
#pragma unroll
        for (int t = 0; t < 8; t++) {
            float ov = __shfl_xor(minv[t], m, 64);
            int oi = __shfl_xor(mini[t], m, 64);
            if (ov < minv[t] || (ov == minv[t] && oi < mini[t])) { minv[t] = ov; mini[t] = oi; }
        }
    }
    if (fr == 0) {
#pragma unroll
        for (int t = 0; t < 8; t++) ridx[wr + (t >> 2) * 16 + q * 4 + (t & 3)] = mini[t];
    }
    __syncthreads();
    // ---- z_q gather (bf16 out) + loss partial: sum (z_q - z)^2 (fp32 z in regs) ----
    float s = 0.f;
#pragma unroll
    for (int i = 0; i < 2; i++)
#pragma unroll
        for (int r = 0; r < 4; r++) {
            int row = wr + i * 16 + q * 4 + r;
            int idx = ridx[row];
#pragma unroll
            for (int j = 0; j < 4; j++) {
                int col = j * 16 + fr;
                float zq = emb[idx * 64 + col];
                float d = zq - acc[i][j][r];
                s += d * d;
                Zq[(row0 + row) * 64 + col] = f2bf(zq);
            }
        }
#pragma unroll
    for (int m = 1; m < 64; m <<= 1) s += __shfl_xor(s, m, 64);
    if (lane == 0) lred[wave] = s;
    __syncthreads();
    if (tid == 0) atomicAdd(lossAcc, lred[0] + lred[1] + lred[2] + lred[3]);
}

__global__ void finish_kernel(const float* __restrict__ lossAcc, float* __restrict__ out) {
    // total loss = 2 * sum / (N*64) = sum / (N*32)
    out[0] = lossAcc[0] * (1.f / (65536.f * 32.f));
}

extern "C" void kernel_launch(void* const* d_in, const int* in_sizes, int n_in,
                              void* d_out, int out_size, void* d_ws, size_t ws_size,
                              hipStream_t stream) {
    const float* x      = (const float*)d_in[0];
    const float* vq_w1  = (const float*)d_in[1];
    const float* vq_b1  = (const float*)d_in[2];
    const float* vq_w2  = (const float*)d_in[3];
    const float* vq_b2  = (const float*)d_in[4];
    const float* emb    = (const float*)d_in[5];
    const float* te_w1  = (const float*)d_in[6];
    const float* te_b1  = (const float*)d_in[7];
    const float* te_w2  = (const float*)d_in[8];
    const float* te_b2  = (const float*)d_in[9];
    const float* mean_w = (const float*)d_in[10];
    const float* mean_b = (const float*)d_in[11];
    const float* lv_w   = (const float*)d_in[12];
    const float* lv_b   = (const float*)d_in[13];
    float* out = (float*)d_out;
    char* ws = (char*)d_ws;
    // workspace layout (bytes)
    ushort_t* xb   = (ushort_t*)(ws + 0LL);          // 64MB, dead after GEMM1
    ushort_t* t1   = (ushort_t*)(ws + 0LL);          // 128MB (reuses xb region)
    ushort_t* h    = (ushort_t*)(ws + 134217728LL);  // 128MB
    ushort_t* t2   = h;                              // reuses h region
    ushort_t* zq   = (ushort_t*)(ws + 268435456LL);  // 8MB
    ushort_t* w1t  = (ushort_t*)(ws + 276824064LL);  // 1MB   [1024,512]
    ushort_t* te2t = (ushort_t*)(ws + 277872640LL);  // 2MB   [1024,1024]
    ushort_t* w2t  = (ushort_t*)(ws + 279969792LL);  // 128KB [64,1024]
    ushort_t* te1t = (ushort_t*)(ws + 280100864LL);  // 128KB [1024,64]
    ushort_t* mwt  = (ushort_t*)(ws + 280231936LL);  // 128KB [64,1024]
    ushort_t* lwt  = (ushort_t*)(ws + 280363008LL);  // 128KB [64,1024]
    float* lossAcc = (float*)(ws + 280494080LL);

    hipMemsetAsync(lossAcc, 0, 4, stream);
    cvt_bf16_kernel<<<32768, 256, 0, stream>>>((const float4*)x, (ushortx4*)xb, 65536 * 512 / 4);
    transpose_cvt_kernel<<<dim3(16, 8), 256, 0, stream>>>(vq_w1, w1t, 512, 1024);
    transpose_cvt_kernel<<<dim3(1, 16), 256, 0, stream>>>(vq_w2, w2t, 1024, 64);
    transpose_cvt_kernel<<<dim3(16, 1), 256, 0, stream>>>(te_w1, te1t, 64, 1024);
    transpose_cvt_kernel<<<dim3(16, 16), 256, 0, stream>>>(te_w2, te2t, 1024, 1024);
    transpose_cvt_kernel<<<dim3(1, 16), 256, 0, stream>>>(mean_w, mwt, 1024, 64);
    transpose_cvt_kernel<<<dim3(1, 16), 256, 0, stream>>>(lv_w, lwt, 1024, 64);

    gemm_bt_kernel<<<dim3(512, 8), 256, 0, stream>>>(xb, w1t, vq_b1, h, 512, 1024, 1);
    vq_kernel<<<512, 256, 0, stream>>>(h, w2t, vq_b2, emb, zq, lossAcc);
    gemm_bt_kernel<<<dim3(512, 8), 256, 0, stream>>>(zq, te1t, te_b1, t1, 64, 1024, 1);
    gemm_bt_kernel<<<dim3(512, 8), 256, 0, stream>>>(t1, te2t, te_b2, t2, 1024, 1024, 1);
    heads_kernel<<<dim3(512, 1), 256, 0, stream>>>(t2, mwt, lwt, mean_b, lv_b, out);
    finish_kernel<<<1, 1, 0, stream>>>(lossAcc, out + 2 * N64);
}

// Round 2
// 668.854 us; speedup vs baseline: 1.1314x; 1.1314x over previous
//
#include <hip/hip_runtime.h>
#include <hip/hip_bf16.h>
#include <stdint.h>

typedef unsigned short ushort_t;
typedef __attribute__((ext_vector_type(8))) short short8;
typedef __attribute__((ext_vector_type(4))) float floatx4;
typedef __attribute__((ext_vector_type(4))) unsigned short ushortx4;

#define N_ROWS 65536
#define N64 4194304LL   // 65536*64

__device__ __forceinline__ ushort_t f2bf(float f) {
    union { float f; unsigned int i; } v; v.f = f;
    unsigned int u = v.i;
    return (ushort_t)((u + 0x7fffu + ((u >> 16) & 1u)) >> 16);
}

__device__ __forceinline__ float fast_tanh(float x) {
    float ax = fabsf(x);
    float t = __expf(-2.f * ax);
    float r = (1.f - t) / (1.f + t);
    return x < 0.f ? -r : r;
}

#define GLD16(gp, lp) __builtin_amdgcn_global_load_lds( \
    (const __attribute__((address_space(1))) unsigned int*)(gp), \
    (__attribute__((address_space(3))) unsigned int*)(lp), 16, 0, 0)

// ---------------- prep: fp32 -> bf16 convert (vectorized) ----------------
__global__ void cvt_bf16_kernel(const float4* __restrict__ src,
                                ushortx4* __restrict__ dst, int n4) {
    int i = blockIdx.x * 256 + threadIdx.x;
    if (i < n4) {
        float4 v = src[i];
        ushortx4 o;
        o.x = f2bf(v.x); o.y = f2bf(v.y); o.z = f2bf(v.z); o.w = f2bf(v.w);
        dst[i] = o;
    }
}

// ---------------- prep: transpose [K,M] fp32 -> [M,K] bf16 ----------------
// grid: (M/64, K/64), block 256
__global__ void transpose_cvt_kernel(const float* __restrict__ src,
                                     ushort_t* __restrict__ dst, int K, int M) {
    __shared__ ushort_t tile[64][65];
    const int m0 = blockIdx.x * 64, k0 = blockIdx.y * 64;
    const int tr = threadIdx.x >> 6, tc = threadIdx.x & 63;
#pragma unroll
    for (int i = 0; i < 16; i++) {
        int kk = i * 4 + tr;
        tile[kk][tc] = f2bf(src[(long)(k0 + kk) * M + m0 + tc]);
    }
    __syncthreads();
#pragma unroll
    for (int i = 0; i < 16; i++) {
        int mm = i * 4 + tr;
        dst[(long)(m0 + mm) * K + k0 + tc] = tile[tc][mm];
    }
}

// ---------------- main bf16 GEMM: C = act(A @ Bt^T + bias) ----------------
// A [N,K] bf16 row-major; Bt [M,K] bf16 row-major; C [N,M] bf16.
// 128x128 tile, BK=32, 4 waves of 4x4 16x16x32 MFMA.
// grid (M/128, N/128): col-block FASTEST so one row-panel's col passes are
// temporally adjacent -> A panel stays in L2/LLC, A fetched from HBM ~once.
__global__ __launch_bounds__(256, 2) void gemm_bt_kernel(
    const ushort_t* __restrict__ A, const ushort_t* __restrict__ Bt,
    const float* __restrict__ bias, ushort_t* __restrict__ C,
    int K, int M, int do_tanh) {
    __shared__ ushort_t As[128 * 32];
    __shared__ ushort_t Bs[128 * 32];
    const int tid = threadIdx.x, wave = tid >> 6, lane = tid & 63;
    const long row0 = (long)blockIdx.y * 128;
    const long col0 = (long)blockIdx.x * 128;
    const int srow = wave * 16 + (lane >> 2);
    const int skoff = (lane & 3) * 8;
    const ushort_t* aG = A + (row0 + srow) * K + skoff;
    const ushort_t* bG = Bt + (col0 + srow) * K + skoff;
    ushort_t* asW = As + wave * 16 * 32;
    ushort_t* bsW = Bs + wave * 16 * 32;
    floatx4 acc[4][4];
#pragma unroll
    for (int i = 0; i < 4; i++)
#pragma unroll
        for (int j = 0; j < 4; j++) acc[i][j] = (floatx4){0.f, 0.f, 0.f, 0.f};
    const int wm = (wave & 1) * 64, wn = (wave >> 1) * 64;
    const int fr = lane & 15, q = lane >> 4, kq = q * 8;
    for (int k0 = 0; k0 < K; k0 += 32) {
        GLD16(aG, asW);
        GLD16(aG + (long)64 * K, asW + 64 * 32);
        GLD16(bG, bsW);
        GLD16(bG + (long)64 * K, bsW + 64 * 32);
        aG += 32; bG += 32;
        __syncthreads();
        short8 af[4], bf[4];
#pragma unroll
        for (int i = 0; i < 4; i++) af[i] = *(const short8*)&As[(wm + i * 16 + fr) * 32 + kq];
#pragma unroll
        for (int j = 0; j < 4; j++) bf[j] = *(const short8*)&Bs[(wn + j * 16 + fr) * 32 + kq];
#pragma unroll
        for (int i = 0; i < 4; i++)
#pragma unroll
            for (int j = 0; j < 4; j++)
                acc[i][j] = __builtin_amdgcn_mfma_f32_16x16x32_bf16(af[i], bf[j], acc[i][j], 0, 0, 0);
        __syncthreads();
    }
    // epilogue: row-outer, col-inner so each 128B line of C is fully written
    // by 4 back-to-back 32B stores (avoids partial-line L2 evictions)
    float bj[4];
#pragma unroll
    for (int j = 0; j < 4; j++) bj[j] = bias[col0 + wn + j * 16 + fr];
#pragma unroll
    for (int i = 0; i < 4; i++) {
        const long rb = row0 + wm + i * 16 + q * 4;
#pragma unroll
        for (int r = 0; r < 4; r++) {
            ushort_t* crow = C + (rb + r) * M + col0 + wn + fr;
#pragma unroll
            for (int j = 0; j < 4; j++) {
                float v = acc[i][j][r] + bj[j];
                if (do_tanh) v = fast_tanh(v);
                crow[j * 16] = f2bf(v);
            }
        }
    }
}

// ---------------- heads: mean & log_var in one pass, fp32 out ----------------
// A = t2 [N,1024]; Mwt/Lwt [64,1024] bf16. grid (N/128, 1).
__global__ __launch_bounds__(256, 2) void heads_kernel(
    const ushort_t* __restrict__ A, const ushort_t* __restrict__ Mwt,
    const ushort_t* __restrict__ Lwt, const float* __restrict__ mb,
    const float* __restrict__ lb, float* __restrict__ out) {
    const int K = 1024;
    __shared__ ushort_t As[128 * 32];
    __shared__ ushort_t Bs[128 * 32];
    const int tid = threadIdx.x, wave = tid >> 6, lane = tid & 63;
    const long row0 = (long)blockIdx.x * 128;
    const int srow = wave * 16 + (lane >> 2);
    const int skoff = (lane & 3) * 8;
    const ushort_t* aG = A + (row0 + srow) * K + skoff;
    const ushort_t* bG0 = Mwt + (long)srow * K + skoff;   // cols 0..63
    const ushort_t* bG1 = Lwt + (long)srow * K + skoff;   // cols 64..127
    ushort_t* asW = As + wave * 16 * 32;
    ushort_t* bsW = Bs + wave * 16 * 32;
    floatx4 acc[4][4];
#pragma unroll
    for (int i = 0; i < 4; i++)
#pragma unroll
        for (int j = 0; j < 4; j++) acc[i][j] = (floatx4){0.f, 0.f, 0.f, 0.f};
    const int wm = (wave & 1) * 64, wn = (wave >> 1) * 64;
    const int fr = lane & 15, q = lane >> 4, kq = q * 8;
    for (int k0 = 0; k0 < K; k0 += 32) {
        GLD16(aG, asW);
        GLD16(aG + (long)64 * K, asW + 64 * 32);
        GLD16(bG0, bsW);
        GLD16(bG1, bsW + 64 * 32);
        aG += 32; bG0 += 32; bG1 += 32;
        __syncthreads();
        short8 af[4], bf[4];
#pragma unroll
        for (int i = 0; i < 4; i++) af[i] = *(const short8*)&As[(wm + i * 16 + fr) * 32 + kq];
#pragma unroll
        for (int j = 0; j < 4; j++) bf[j] = *(const short8*)&Bs[(wn + j * 16 + fr) * 32 + kq];
#pragma unroll
        for (int i = 0; i < 4; i++)
#pragma unroll
            for (int j = 0; j < 4; j++)
                acc[i][j] = __builtin_amdgcn_mfma_f32_16x16x32_bf16(af[i], bf[j], acc[i][j], 0, 0, 0);
        __syncthreads();
    }
    // epilogue, row-outer: full 64B/128B line segments written back-to-back
    float bj[4];
    float* ob[4];
#pragma unroll
    for (int j = 0; j < 4; j++) {
        const int c = wn + j * 16 + fr;   // 0..127
        bj[j] = (c < 64) ? mb[c] : lb[c - 64];
        ob[j] = (c < 64) ? (out + c) : (out + N64 + (c - 64));
    }
#pragma unroll
    for (int i = 0; i < 4; i++) {
        const long rb = row0 + wm + i * 16 + q * 4;
#pragma unroll
        for (int r = 0; r < 4; r++) {
#pragma unroll
            for (int j = 0; j < 4; j++) ob[j][(rb + r) * 64] = acc[i][j][r] + bj[j];
        }
    }
}

// ---------------- fused VQ: z-GEMM + argmin + z_q gather + loss ----------------
// grid N/128 blocks. H [N,1024] bf16, W2t [64,1024] bf16, emb [512,64] fp32.
__global__ __launch_bounds__(256, 1) void vq_kernel(
    const ushort_t* __restrict__ H, const ushort_t* __restrict__ W2t,
    const float* __restrict__ b2, const float* __restrict__ emb,
    ushort_t* __restrict__ Zq, float* __restrict__ lossAcc) {
    const int K = 1024;
    __shared__ ushort_t As[128 * 32];   // 8KB
    __shared__ ushort_t Bs[64 * 32];    // 4KB
    __shared__ ushort_t zb[128 * 64];   // 16KB  z in bf16, A-operand staging
    __shared__ ushort_t ebc[128 * 64];  // 16KB  codebook chunk bf16
    __shared__ float enorm[512];
    __shared__ int ridx[128];
    __shared__ float lred[4];
    const int tid = threadIdx.x, wave = tid >> 6, lane = tid & 63;
    const long row0 = (long)blockIdx.x * 128;
    const int srow = wave * 16 + (lane >> 2), skoff = (lane & 3) * 8;
    const ushort_t* aG = H + (row0 + srow) * K + skoff;
    const ushort_t* bG = W2t + (long)srow * K + skoff;
    ushort_t* asW = As + wave * 16 * 32;
    ushort_t* bsW = Bs + wave * 16 * 32;
    floatx4 acc[2][4];
#pragma unroll
    for (int i = 0; i < 2; i++)
#pragma unroll
        for (int j = 0; j < 4; j++) acc[i][j] = (floatx4){0.f, 0.f, 0.f, 0.f};
    const int fr = lane & 15, q = lane >> 4, kq = q * 8;
    const int wr = wave * 32;
    // ---- z = H @ W2t^T + b2 ----
    for (int k0 = 0; k0 < K; k0 += 32) {
        GLD16(aG, asW);
        GLD16(aG + (long)64 * K, asW + 64 * 32);
        GLD16(bG, bsW);
        aG += 32; bG += 32;
        __syncthreads();
        short8 af[2], bf[4];
#pragma unroll
        for (int i = 0; i < 2; i++) af[i] = *(const short8*)&As[(wr + i * 16 + fr) * 32 + kq];
#pragma unroll
        for (int j = 0; j < 4; j++) bf[j] = *(const short8*)&Bs[(j * 16 + fr) * 32 + kq];
#pragma unroll
        for (int i = 0; i < 2; i++)
#pragma unroll
            for (int j = 0; j < 4; j++)
                acc[i][j] = __builtin_amdgcn_mfma_f32_16x16x32_bf16(af[i], bf[j], acc[i][j], 0, 0, 0);
        __syncthreads();
    }
    // add bias, stage z (bf16) for the distance MFMA
#pragma unroll
    for (int j = 0; j < 4; j++) {
        float bb = b2[j * 16 + fr];
#pragma unroll
        for (int i = 0; i < 2; i++)
#pragma unroll
            for (int r = 0; r < 4; r++) {
                acc[i][j][r] += bb;
                zb[(wr + i * 16 + q * 4 + r) * 64 + j * 16 + fr] = f2bf(acc[i][j][r]);
            }
    }
    // codebook squared norms (fp32, from global)
    for (int c = tid; c < 512; c += 256) {
        const float4* e = (const float4*)(emb + c * 64);
        float s = 0.f;
#pragma unroll
        for (int k = 0; k < 16; k++) { float4 v = e[k]; s += v.x * v.x + v.y * v.y + v.z * v.z + v.w * v.w; }
        enorm[c] = s;
    }
    __syncthreads();
    // z fragments (A-operand layout) — rows of this wave
    short8 za[2][2];
#pragma unroll
    for (int i = 0; i < 2; i++)
#pragma unroll
        for (int h = 0; h < 2; h++)
            za[i][h] = *(const short8*)&zb[(wr + i * 16 + fr) * 64 + h * 32 + kq];
    float minv[8]; int mini[8];
#pragma unroll
    for (int t = 0; t < 8; t++) { minv[t] = 3.0e38f; mini[t] = 0; }
    // ---- dist = ||e||^2 - 2 z.e, chunked 128 codes ----
    for (int ch = 0; ch < 4; ch++) {
        __syncthreads();   // previous chunk's MFMAs done before restage
        const float4* esrc = (const float4*)(emb + ch * 128 * 64);
        for (int g = tid; g < 2048; g += 256) {
            float4 v = esrc[g];
            ushortx4 o;
            o.x = f2bf(v.x); o.y = f2bf(v.y); o.z = f2bf(v.z); o.w = f2bf(v.w);
            *(ushortx4*)&ebc[g * 4] = o;
        }
        __syncthreads();
#pragma unroll
        for (int jt = 0; jt < 8; jt++) {
            const int code = ch * 128 + jt * 16 + fr;
            short8 e0 = *(const short8*)&ebc[(jt * 16 + fr) * 64 + kq];
            short8 e1 = *(const short8*)&ebc[(jt * 16 + fr) * 64 + 32 + kq];
            float en = enorm[code];
#pragma unroll
            for (int i = 0; i < 2; i++) {
                floatx4 s = (floatx4){0.f, 0.f, 0.f, 0.f};
                s = __builtin_amdgcn_mfma_f32_16x16x32_bf16(za[i][0], e0, s, 0, 0, 0);
                s = __builtin_amdgcn_mfma_f32_16x16x32_bf16(za[i][1], e1, s, 0, 0, 0);
#pragma unroll
                for (int r = 0; r < 4; r++) {
                    float d = en - 2.f * s[r];
                    int t = i * 4 + r;
                    if (d < minv[t]) { minv[t] = d; mini[t] = code; }
                }
            }
        }
    }
    // reduce argmin across the 16 lanes that share each output row
#pragma unroll
    for (int m = 1; m < 16; m <<= 1) {
#pragma unroll
        for (int t = 0; t < 8; t++) {
            float ov = __shfl_xor(minv[t], m, 64);
            int oi = __shfl_xor(mini[t], m, 64);
            if (ov < minv[t] || (ov == minv[t] && oi < mini[t])) { minv[t] = ov; mini[t] = oi; }
        }
    }
    if (fr == 0) {
#pragma unroll
        for (int t = 0; t < 8; t++) ridx[wr + (t >> 2) * 16 + q * 4 + (t & 3)] = mini[t];
    }
    __syncthreads();
    // ---- z_q gather (bf16 out) + loss partial: sum (z_q - z)^2 (fp32 z in regs) ----
    float s = 0.f;
#pragma unroll
    for (int i = 0; i < 2; i++)
#pragma unroll
        for (int r = 0; r < 4; r++) {
            int row = wr + i * 16 + q * 4 + r;
            int idx = ridx[row];
#pragma unroll
            for (int j = 0; j < 4; j++) {
                int col = j * 16 + fr;
                float zq = emb[idx * 64 + col];
                float d = zq - acc[i][j][r];
                s += d * d;
                Zq[(row0 + row) * 64 + col] = f2bf(zq);
            }
        }
#pragma unroll
    for (int m = 1; m < 64; m <<= 1) s += __shfl_xor(s, m, 64);
    if (lane == 0) lred[wave] = s;
    __syncthreads();
    if (tid == 0) atomicAdd(lossAcc, lred[0] + lred[1] + lred[2] + lred[3]);
}

__global__ void finish_kernel(const float* __restrict__ lossAcc, float* __restrict__ out) {
    // total loss = 2 * sum / (N*64) = sum / (N*32)
    out[0] = lossAcc[0] * (1.f / (65536.f * 32.f));
}

extern "C" void kernel_launch(void* const* d_in, const int* in_sizes, int n_in,
                              void* d_out, int out_size, void* d_ws, size_t ws_size,
                              hipStream_t stream) {
    const float* x      = (const float*)d_in[0];
    const float* vq_w1  = (const float*)d_in[1];
    const float* vq_b1  = (const float*)d_in[2];
    const float* vq_w2  = (const float*)d_in[3];
    const float* vq_b2  = (const float*)d_in[4];
    const float* emb    = (const float*)d_in[5];
    const float* te_w1  = (const float*)d_in[6];
    const float* te_b1  = (const float*)d_in[7];
    const float* te_w2  = (const float*)d_in[8];
    const float* te_b2  = (const float*)d_in[9];
    const float* mean_w = (const float*)d_in[10];
    const float* mean_b = (const float*)d_in[11];
    const float* lv_w   = (const float*)d_in[12];
    const float* lv_b   = (const float*)d_in[13];
    float* out = (float*)d_out;
    char* ws = (char*)d_ws;
    // workspace layout (bytes)
    ushort_t* xb   = (ushort_t*)(ws + 0LL);          // 64MB, dead after GEMM1
    ushort_t* t1   = (ushort_t*)(ws + 0LL);          // 128MB (reuses xb region)
    ushort_t* h    = (ushort_t*)(ws + 134217728LL);  // 128MB
    ushort_t* t2   = h;                              // reuses h region
    ushort_t* zq   = (ushort_t*)(ws + 268435456LL);  // 8MB
    ushort_t* w1t  = (ushort_t*)(ws + 276824064LL);  // 1MB   [1024,512]
    ushort_t* te2t = (ushort_t*)(ws + 277872640LL);  // 2MB   [1024,1024]
    ushort_t* w2t  = (ushort_t*)(ws + 279969792LL);  // 128KB [64,1024]
    ushort_t* te1t = (ushort_t*)(ws + 280100864LL);  // 128KB [1024,64]
    ushort_t* mwt  = (ushort_t*)(ws + 280231936LL);  // 128KB [64,1024]
    ushort_t* lwt  = (ushort_t*)(ws + 280363008LL);  // 128KB [64,1024]
    float* lossAcc = (float*)(ws + 280494080LL);

    hipMemsetAsync(lossAcc, 0, 4, stream);
    cvt_bf16_kernel<<<32768, 256, 0, stream>>>((const float4*)x, (ushortx4*)xb, 65536 * 512 / 4);
    transpose_cvt_kernel<<<dim3(16, 8), 256, 0, stream>>>(vq_w1, w1t, 512, 1024);
    transpose_cvt_kernel<<<dim3(1, 16), 256, 0, stream>>>(vq_w2, w2t, 1024, 64);
    transpose_cvt_kernel<<<dim3(16, 1), 256, 0, stream>>>(te_w1, te1t, 64, 1024);
    transpose_cvt_kernel<<<dim3(16, 16), 256, 0, stream>>>(te_w2, te2t, 1024, 1024);
    transpose_cvt_kernel<<<dim3(1, 16), 256, 0, stream>>>(mean_w, mwt, 1024, 64);
    transpose_cvt_kernel<<<dim3(1, 16), 256, 0, stream>>>(lv_w, lwt, 1024, 64);

    // col-block fastest (x = col): row-panel locality in L2/LLC
    gemm_bt_kernel<<<dim3(8, 512), 256, 0, stream>>>(xb, w1t, vq_b1, h, 512, 1024, 1);
    vq_kernel<<<512, 256, 0, stream>>>(h, w2t, vq_b2, emb, zq, lossAcc);
    gemm_bt_kernel<<<dim3(8, 512), 256, 0, stream>>>(zq, te1t, te_b1, t1, 64, 1024, 1);
    gemm_bt_kernel<<<dim3(8, 512), 256, 0, stream>>>(t1, te2t, te_b2, t2, 1024, 1024, 1);
    heads_kernel<<<dim3(512, 1), 256, 0, stream>>>(t2, mwt, lwt, mean_b, lv_b, out);
    finish_kernel<<<1, 1, 0, stream>>>(lossAcc, out + 2 * N64);
}

// Round 3
// 451.458 us; speedup vs baseline: 1.6762x; 1.4815x over previous
//
#include <hip/hip_runtime.h>
#include <hip/hip_bf16.h>
#include <stdint.h>

typedef unsigned short ushort_t;
typedef __attribute__((ext_vector_type(8))) short short8;
typedef __attribute__((ext_vector_type(4))) float floatx4;
typedef __attribute__((ext_vector_type(4))) unsigned short ushortx4;

#define N_ROWS 65536
#define N64 4194304LL   // 65536*64

__device__ __forceinline__ ushort_t f2bf(float f) {
    union { float f; unsigned int i; } v; v.f = f;
    unsigned int u = v.i;
    return (ushort_t)((u + 0x7fffu + ((u >> 16) & 1u)) >> 16);
}

__device__ __forceinline__ float fast_tanh(float x) {
    float ax = fabsf(x);
    float t = __expf(-2.f * ax);
    float r = (1.f - t) / (1.f + t);
    return x < 0.f ? -r : r;
}

#define GLD16(gp, lp) __builtin_amdgcn_global_load_lds( \
    (const __attribute__((address_space(1))) unsigned int*)(gp), \
    (__attribute__((address_space(3))) unsigned int*)(lp), 16, 0, 0)

// ---------------- prep: fp32 -> bf16 convert (vectorized) ----------------
__global__ void cvt_bf16_kernel(const float4* __restrict__ src,
                                ushortx4* __restrict__ dst, int n4) {
    int i = blockIdx.x * 256 + threadIdx.x;
    if (i < n4) {
        float4 v = src[i];
        ushortx4 o;
        o.x = f2bf(v.x); o.y = f2bf(v.y); o.z = f2bf(v.z); o.w = f2bf(v.w);
        dst[i] = o;
    }
}

// ---------------- prep: transpose [K,M] fp32 -> [M,K] bf16 ----------------
// grid: (M/64, K/64), block 256
__global__ void transpose_cvt_kernel(const float* __restrict__ src,
                                     ushort_t* __restrict__ dst, int K, int M) {
    __shared__ ushort_t tile[64][65];
    const int m0 = blockIdx.x * 64, k0 = blockIdx.y * 64;
    const int tr = threadIdx.x >> 6, tc = threadIdx.x & 63;
#pragma unroll
    for (int i = 0; i < 16; i++) {
        int kk = i * 4 + tr;
        tile[kk][tc] = f2bf(src[(long)(k0 + kk) * M + m0 + tc]);
    }
    __syncthreads();
#pragma unroll
    for (int i = 0; i < 16; i++) {
        int mm = i * 4 + tr;
        dst[(long)(m0 + mm) * K + k0 + tc] = tile[tc][mm];
    }
}

// ---------------- main bf16 GEMM: C = act(A @ Bt^T + bias) ----------------
// A [N,K] bf16 row-major; Bt [M,K] bf16 row-major; C [N,M] bf16.
// 128x128 tile, BK=32, 4 waves of 4x4 16x16x32 MFMA.
// swizzled mode (1-D grid, ncol=8): xcd = bid&7; a row-panel's 8 col-blocks
// get bids {xcd + 8k, k consecutive} -> same XCD, temporally adjacent ->
// A panel + B stay resident in that XCD's 4MB L2.
__global__ __launch_bounds__(256, 2) void gemm_bt_kernel(
    const ushort_t* __restrict__ A, const ushort_t* __restrict__ Bt,
    const float* __restrict__ bias, ushort_t* __restrict__ C,
    int K, int M, int do_tanh, int swizzled) {
    __shared__ ushort_t As[128 * 32];
    __shared__ ushort_t Bs[128 * 32];
    const int tid = threadIdx.x, wave = tid >> 6, lane = tid & 63;
    long row0, col0;
    if (swizzled) {
        const int bid = blockIdx.x;
        const int xcd = bid & 7, k = bid >> 3;
        row0 = (long)((k >> 3) * 8 + xcd) * 128;
        col0 = (long)(k & 7) * 128;
    } else {
        row0 = (long)blockIdx.y * 128;
        col0 = (long)blockIdx.x * 128;
    }
    const int srow = wave * 16 + (lane >> 2);
    const int skoff = (lane & 3) * 8;
    const ushort_t* aG = A + (row0 + srow) * K + skoff;
    const ushort_t* bG = Bt + (col0 + srow) * K + skoff;
    ushort_t* asW = As + wave * 16 * 32;
    ushort_t* bsW = Bs + wave * 16 * 32;
    floatx4 acc[4][4];
#pragma unroll
    for (int i = 0; i < 4; i++)
#pragma unroll
        for (int j = 0; j < 4; j++) acc[i][j] = (floatx4){0.f, 0.f, 0.f, 0.f};
    const int wm = (wave & 1) * 64, wn = (wave >> 1) * 64;
    const int fr = lane & 15, q = lane >> 4, kq = q * 8;
    for (int k0 = 0; k0 < K; k0 += 32) {
        GLD16(aG, asW);
        GLD16(aG + (long)64 * K, asW + 64 * 32);
        GLD16(bG, bsW);
        GLD16(bG + (long)64 * K, bsW + 64 * 32);
        aG += 32; bG += 32;
        __syncthreads();
        short8 af[4], bf[4];
#pragma unroll
        for (int i = 0; i < 4; i++) af[i] = *(const short8*)&As[(wm + i * 16 + fr) * 32 + kq];
#pragma unroll
        for (int j = 0; j < 4; j++) bf[j] = *(const short8*)&Bs[(wn + j * 16 + fr) * 32 + kq];
#pragma unroll
        for (int i = 0; i < 4; i++)
#pragma unroll
            for (int j = 0; j < 4; j++)
                acc[i][j] = __builtin_amdgcn_mfma_f32_16x16x32_bf16(af[i], bf[j], acc[i][j], 0, 0, 0);
        __syncthreads();
    }
    // epilogue: row-outer, col-inner so each 128B line of C is fully written
    float bj[4];
#pragma unroll
    for (int j = 0; j < 4; j++) bj[j] = bias[col0 + wn + j * 16 + fr];
#pragma unroll
    for (int i = 0; i < 4; i++) {
        const long rb = row0 + wm + i * 16 + q * 4;
#pragma unroll
        for (int r = 0; r < 4; r++) {
            ushort_t* crow = C + (rb + r) * M + col0 + wn + fr;
#pragma unroll
            for (int j = 0; j < 4; j++) {
                float v = acc[i][j][r] + bj[j];
                if (do_tanh) v = fast_tanh(v);
                crow[j * 16] = f2bf(v);
            }
        }
    }
}

// ---------------- heads table: mean & log_var over 512 codebook rows ----------------
// A = t2tab [512,1024] bf16; Mwt/Lwt [64,1024] bf16. grid (4). fp32 tables out.
__global__ __launch_bounds__(256, 2) void heads_tab_kernel(
    const ushort_t* __restrict__ A, const ushort_t* __restrict__ Mwt,
    const ushort_t* __restrict__ Lwt, const float* __restrict__ mb,
    const float* __restrict__ lb, float* __restrict__ meanTab,
    float* __restrict__ lvTab) {
    const int K = 1024;
    __shared__ ushort_t As[128 * 32];
    __shared__ ushort_t Bs[128 * 32];
    const int tid = threadIdx.x, wave = tid >> 6, lane = tid & 63;
    const long row0 = (long)blockIdx.x * 128;
    const int srow = wave * 16 + (lane >> 2);
    const int skoff = (lane & 3) * 8;
    const ushort_t* aG = A + (row0 + srow) * K + skoff;
    const ushort_t* bG0 = Mwt + (long)srow * K + skoff;   // cols 0..63
    const ushort_t* bG1 = Lwt + (long)srow * K + skoff;   // cols 64..127
    ushort_t* asW = As + wave * 16 * 32;
    ushort_t* bsW = Bs + wave * 16 * 32;
    floatx4 acc[4][4];
#pragma unroll
    for (int i = 0; i < 4; i++)
#pragma unroll
        for (int j = 0; j < 4; j++) acc[i][j] = (floatx4){0.f, 0.f, 0.f, 0.f};
    const int wm = (wave & 1) * 64, wn = (wave >> 1) * 64;
    const int fr = lane & 15, q = lane >> 4, kq = q * 8;
    for (int k0 = 0; k0 < K; k0 += 32) {
        GLD16(aG, asW);
        GLD16(aG + (long)64 * K, asW + 64 * 32);
        GLD16(bG0, bsW);
        GLD16(bG1, bsW + 64 * 32);
        aG += 32; bG0 += 32; bG1 += 32;
        __syncthreads();
        short8 af[4], bf[4];
#pragma unroll
        for (int i = 0; i < 4; i++) af[i] = *(const short8*)&As[(wm + i * 16 + fr) * 32 + kq];
#pragma unroll
        for (int j = 0; j < 4; j++) bf[j] = *(const short8*)&Bs[(wn + j * 16 + fr) * 32 + kq];
#pragma unroll
        for (int i = 0; i < 4; i++)
#pragma unroll
            for (int j = 0; j < 4; j++)
                acc[i][j] = __builtin_amdgcn_mfma_f32_16x16x32_bf16(af[i], bf[j], acc[i][j], 0, 0, 0);
        __syncthreads();
    }
    float bj[4];
    float* ob[4];
#pragma unroll
    for (int j = 0; j < 4; j++) {
        const int c = wn + j * 16 + fr;   // 0..127
        bj[j] = (c < 64) ? mb[c] : lb[c - 64];
        ob[j] = (c < 64) ? (meanTab + c) : (lvTab + (c - 64));
    }
#pragma unroll
    for (int i = 0; i < 4; i++) {
        const long rb = row0 + wm + i * 16 + q * 4;
#pragma unroll
        for (int r = 0; r < 4; r++) {
#pragma unroll
            for (int j = 0; j < 4; j++) ob[j][(rb + r) * 64] = acc[i][j][r] + bj[j];
        }
    }
}

// ---------------- fused VQ: z-GEMM + argmin + idx out + loss ----------------
// grid N/128 blocks. H [N,1024] bf16, W2t [64,1024] bf16, emb [512,64] fp32.
__global__ __launch_bounds__(256, 1) void vq_kernel(
    const ushort_t* __restrict__ H, const ushort_t* __restrict__ W2t,
    const float* __restrict__ b2, const float* __restrict__ emb,
    int* __restrict__ idxOut, float* __restrict__ lossAcc) {
    const int K = 1024;
    __shared__ ushort_t As[128 * 32];   // 8KB
    __shared__ ushort_t Bs[64 * 32];    // 4KB
    __shared__ ushort_t zb[128 * 64];   // 16KB  z in bf16, A-operand staging
    __shared__ ushort_t ebc[128 * 64];  // 16KB  codebook chunk bf16
    __shared__ float enorm[512];
    __shared__ int ridx[128];
    __shared__ float lred[4];
    const int tid = threadIdx.x, wave = tid >> 6, lane = tid & 63;
    const long row0 = (long)blockIdx.x * 128;
    const int srow = wave * 16 + (lane >> 2), skoff = (lane & 3) * 8;
    const ushort_t* aG = H + (row0 + srow) * K + skoff;
    const ushort_t* bG = W2t + (long)srow * K + skoff;
    ushort_t* asW = As + wave * 16 * 32;
    ushort_t* bsW = Bs + wave * 16 * 32;
    floatx4 acc[2][4];
#pragma unroll
    for (int i = 0; i < 2; i++)
#pragma unroll
        for (int j = 0; j < 4; j++) acc[i][j] = (floatx4){0.f, 0.f, 0.f, 0.f};
    const int fr = lane & 15, q = lane >> 4, kq = q * 8;
    const int wr = wave * 32;
    // ---- z = H @ W2t^T + b2 ----
    for (int k0 = 0; k0 < K; k0 += 32) {
        GLD16(aG, asW);
        GLD16(aG + (long)64 * K, asW + 64 * 32);
        GLD16(bG, bsW);
        aG += 32; bG += 32;
        __syncthreads();
        short8 af[2], bf[4];
#pragma unroll
        for (int i = 0; i < 2; i++) af[i] = *(const short8*)&As[(wr + i * 16 + fr) * 32 + kq];
#pragma unroll
        for (int j = 0; j < 4; j++) bf[j] = *(const short8*)&Bs[(j * 16 + fr) * 32 + kq];
#pragma unroll
        for (int i = 0; i < 2; i++)
#pragma unroll
            for (int j = 0; j < 4; j++)
                acc[i][j] = __builtin_amdgcn_mfma_f32_16x16x32_bf16(af[i], bf[j], acc[i][j], 0, 0, 0);
        __syncthreads();
    }
    // add bias, stage z (bf16) for the distance MFMA
#pragma unroll
    for (int j = 0; j < 4; j++) {
        float bb = b2[j * 16 + fr];
#pragma unroll
        for (int i = 0; i < 2; i++)
#pragma unroll
            for (int r = 0; r < 4; r++) {
                acc[i][j][r] += bb;
                zb[(wr + i * 16 + q * 4 + r) * 64 + j * 16 + fr] = f2bf(acc[i][j][r]);
            }
    }
    // codebook squared norms (fp32, from global)
    for (int c = tid; c < 512; c += 256) {
        const float4* e = (const float4*)(emb + c * 64);
        float s = 0.f;
#pragma unroll
        for (int k = 0; k < 16; k++) { float4 v = e[k]; s += v.x * v.x + v.y * v.y + v.z * v.z + v.w * v.w; }
        enorm[c] = s;
    }
    __syncthreads();
    // z fragments (A-operand layout) — rows of this wave
    short8 za[2][2];
#pragma unroll
    for (int i = 0; i < 2; i++)
#pragma unroll
        for (int h = 0; h < 2; h++)
            za[i][h] = *(const short8*)&zb[(wr + i * 16 + fr) * 64 + h * 32 + kq];
    float minv[8]; int mini[8];
#pragma unroll
    for (int t = 0; t < 8; t++) { minv[t] = 3.0e38f; mini[t] = 0; }
    // ---- dist = ||e||^2 - 2 z.e, chunked 128 codes ----
    for (int ch = 0; ch < 4; ch++) {
        __syncthreads();   // previous chunk's MFMAs done before restage
        const float4* esrc = (const float4*)(emb + ch * 128 * 64);
        for (int g = tid; g < 2048; g += 256) {
            float4 v = esrc[g];
            ushortx4 o;
            o.x = f2bf(v.x); o.y = f2bf(v.y); o.z = f2bf(v.z); o.w = f2bf(v.w);
            *(ushortx4*)&ebc[g * 4] = o;
        }
        __syncthreads();
#pragma unroll
        for (int jt = 0; jt < 8; jt++) {
            const int code = ch * 128 + jt * 16 + fr;
            short8 e0 = *(const short8*)&ebc[(jt * 16 + fr) * 64 + kq];
            short8 e1 = *(const short8*)&ebc[(jt * 16 + fr) * 64 + 32 + kq];
            float en = enorm[code];
#pragma unroll
            for (int i = 0; i < 2; i++) {
                floatx4 s = (floatx4){0.f, 0.f, 0.f, 0.f};
                s = __builtin_amdgcn_mfma_f32_16x16x32_bf16(za[i][0], e0, s, 0, 0, 0);
                s = __builtin_amdgcn_mfma_f32_16x16x32_bf16(za[i][1], e1, s, 0, 0, 0);
#pragma unroll
                for (int r = 0; r < 4; r++) {
                    float d = en - 2.f * s[r];
                    int t = i * 4 + r;
                    if (d < minv[t]) { minv[t] = d; mini[t] = code; }
                }
            }
        }
    }
    // reduce argmin across the 16 lanes that share each output row
#pragma unroll
    for (int m = 1; m < 16; m <<= 1) {
#pragma unroll
        for (int t = 0; t < 8; t++) {
            float ov = __shfl_xor(minv[t], m, 64);
            int oi = __shfl_xor(mini[t], m, 64);
            if (ov < minv[t] || (ov == minv[t] && oi < mini[t])) { minv[t] = ov; mini[t] = oi; }
        }
    }
    if (fr == 0) {
#pragma unroll
        for (int t = 0; t < 8; t++) {
            int row = wr + (t >> 2) * 16 + q * 4 + (t & 3);
            ridx[row] = mini[t];
            idxOut[row0 + row] = mini[t];
        }
    }
    __syncthreads();
    // ---- loss partial: sum (z_q - z)^2 (fp32 z in regs, fp32 emb gather) ----
    float s = 0.f;
#pragma unroll
    for (int i = 0; i < 2; i++)
#pragma unroll
        for (int r = 0; r < 4; r++) {
            int row = wr + i * 16 + q * 4 + r;
            int idx = ridx[row];
#pragma unroll
            for (int j = 0; j < 4; j++) {
                int col = j * 16 + fr;
                float zq = emb[idx * 64 + col];
                float d = zq - acc[i][j][r];
                s += d * d;
            }
        }
#pragma unroll
    for (int m = 1; m < 64; m <<= 1) s += __shfl_xor(s, m, 64);
    if (lane == 0) lred[wave] = s;
    __syncthreads();
    if (tid == 0) atomicAdd(lossAcc, lred[0] + lred[1] + lred[2] + lred[3]);
}

// ---------------- gather: out rows from 512-entry tables ----------------
// 16 threads per row, one float4 each. grid 4096 x 256.
__global__ void gather_out_kernel(const int* __restrict__ idx,
                                  const float4* __restrict__ meanTab,
                                  const float4* __restrict__ lvTab,
                                  float4* __restrict__ out) {
    int g = blockIdx.x * 256 + threadIdx.x;   // 0 .. 65536*16
    int row = g >> 4, part = g & 15;
    int id = idx[row];
    out[g] = meanTab[id * 16 + part];
    out[1048576 + g] = lvTab[id * 16 + part];   // N64/4 float4 offset
}

__global__ void finish_kernel(const float* __restrict__ lossAcc, float* __restrict__ out) {
    // total loss = 2 * sum / (N*64) = sum / (N*32)
    out[0] = lossAcc[0] * (1.f / (65536.f * 32.f));
}

extern "C" void kernel_launch(void* const* d_in, const int* in_sizes, int n_in,
                              void* d_out, int out_size, void* d_ws, size_t ws_size,
                              hipStream_t stream) {
    const float* x      = (const float*)d_in[0];
    const float* vq_w1  = (const float*)d_in[1];
    const float* vq_b1  = (const float*)d_in[2];
    const float* vq_w2  = (const float*)d_in[3];
    const float* vq_b2  = (const float*)d_in[4];
    const float* emb    = (const float*)d_in[5];
    const float* te_w1  = (const float*)d_in[6];
    const float* te_b1  = (const float*)d_in[7];
    const float* te_w2  = (const float*)d_in[8];
    const float* te_b2  = (const float*)d_in[9];
    const float* mean_w = (const float*)d_in[10];
    const float* mean_b = (const float*)d_in[11];
    const float* lv_w   = (const float*)d_in[12];
    const float* lv_b   = (const float*)d_in[13];
    float* out = (float*)d_out;
    char* ws = (char*)d_ws;
    // workspace layout (bytes)
    ushort_t* xb      = (ushort_t*)(ws + 0LL);          // 64MB
    ushort_t* h       = (ushort_t*)(ws + 134217728LL);  // 128MB
    ushort_t* w1t     = (ushort_t*)(ws + 268435456LL);  // 1MB   [1024,512]
    ushort_t* te2t    = (ushort_t*)(ws + 269484032LL);  // 2MB   [1024,1024]
    ushort_t* w2t     = (ushort_t*)(ws + 271581184LL);  // 128KB [64,1024]
    ushort_t* te1t    = (ushort_t*)(ws + 271712256LL);  // 128KB [1024,64]
    ushort_t* mwt     = (ushort_t*)(ws + 271843328LL);  // 128KB [64,1024]
    ushort_t* lwt     = (ushort_t*)(ws + 271974400LL);  // 128KB [64,1024]
    ushort_t* embb    = (ushort_t*)(ws + 272105472LL);  // 64KB  [512,64] bf16
    ushort_t* t1tab   = (ushort_t*)(ws + 272171008LL);  // 1MB   [512,1024] bf16
    ushort_t* t2tab   = (ushort_t*)(ws + 273219584LL);  // 1MB   [512,1024] bf16
    float*    meanTab = (float*)   (ws + 274268160LL);  // 128KB [512,64] fp32
    float*    lvTab   = (float*)   (ws + 274399232LL);  // 128KB [512,64] fp32
    int*      idxbuf  = (int*)     (ws + 274530304LL);  // 256KB [65536] int32
    float*    lossAcc = (float*)   (ws + 274792448LL);  // 4B

    hipMemsetAsync(lossAcc, 0, 4, stream);
    cvt_bf16_kernel<<<32768, 256, 0, stream>>>((const float4*)x, (ushortx4*)xb, 65536 * 512 / 4);
    cvt_bf16_kernel<<<32, 256, 0, stream>>>((const float4*)emb, (ushortx4*)embb, 512 * 64 / 4);
    transpose_cvt_kernel<<<dim3(16, 8), 256, 0, stream>>>(vq_w1, w1t, 512, 1024);
    transpose_cvt_kernel<<<dim3(1, 16), 256, 0, stream>>>(vq_w2, w2t, 1024, 64);
    transpose_cvt_kernel<<<dim3(16, 1), 256, 0, stream>>>(te_w1, te1t, 64, 1024);
    transpose_cvt_kernel<<<dim3(16, 16), 256, 0, stream>>>(te_w2, te2t, 1024, 1024);
    transpose_cvt_kernel<<<dim3(1, 16), 256, 0, stream>>>(mean_w, mwt, 1024, 64);
    transpose_cvt_kernel<<<dim3(1, 16), 256, 0, stream>>>(lv_w, lwt, 1024, 64);

    // GEMM1: h = tanh(x @ vq_w1 + b1)   [65536,1024], XCD-swizzled 1-D grid
    gemm_bt_kernel<<<4096, 256, 0, stream>>>(xb, w1t, vq_b1, h, 512, 1024, 1, 1);
    // VQ: idx + loss only
    vq_kernel<<<512, 256, 0, stream>>>(h, w2t, vq_b2, emb, idxbuf, lossAcc);
    // 512-row task-embedding tables (post-VQ pipeline is a function of idx only)
    gemm_bt_kernel<<<dim3(8, 4), 256, 0, stream>>>(embb, te1t, te_b1, t1tab, 64, 1024, 1, 0);
    gemm_bt_kernel<<<dim3(8, 4), 256, 0, stream>>>(t1tab, te2t, te_b2, t2tab, 1024, 1024, 1, 0);
    heads_tab_kernel<<<4, 256, 0, stream>>>(t2tab, mwt, lwt, mean_b, lv_b, meanTab, lvTab);
    // scatter table rows to the 65536-row outputs
    gather_out_kernel<<<4096, 256, 0, stream>>>(idxbuf, (const float4*)meanTab,
                                                (const float4*)lvTab, (float4*)out);
    finish_kernel<<<1, 1, 0, stream>>>(lossAcc, out + 2 * N64);
}